// Round 9
// baseline (267.738 us; speedup 1.0000x reference)
//
#include <hip/hip_runtime.h>
#include <hip/hip_bf16.h>
#include <stdint.h>
#include <math.h>

#define BB 32768
#define FEAT 512
#define SPD_H 128
#define CTRL_H 256
#define NCMD 4

typedef __attribute__((ext_vector_type(8))) short bf16x8;
typedef __attribute__((ext_vector_type(4))) float f32x4;

__device__ __forceinline__ unsigned short f2bf(float f) {
  union { float f; uint32_t u; } v; v.f = f;
  uint32_t u = v.u;
  return (unsigned short)((u + 0x7fffu + ((u >> 16) & 1u)) >> 16); // RNE
}

// async global->LDS, 16B per lane; LDS dest = wave-uniform base + lane*16
__device__ __forceinline__ void async16(const unsigned short* g, unsigned short* l) {
  __builtin_amdgcn_global_load_lds(
      (const __attribute__((address_space(1))) unsigned int*)g,
      (__attribute__((address_space(3))) unsigned int*)l, 16, 0, 0);
}

// ------ fused prep: feat convert + wjbf convert + weight transposes + count ---
struct WSeg { const float* src; unsigned short* dst; int K; int N; int ldd; };
struct PrepArgs {
  WSeg s[12];
  int start[13];
  const float* join_w; unsigned short* wjbf;   // straight f32->bf16, [640][512]
  const float* feat; unsigned short* ajoin;
  const int* cmd; int* wavecnt;
};
__global__ void k_prep(PrepArgs a) {
  int bx = blockIdx.x, t = threadIdx.x;
  if (bx < 16384) {          // feat f32 -> bf16 into ajoin[:,0:512] (stride 640)
    int idx = bx * 256 + t;
    int i = idx >> 7;
    int j4 = (idx & 127) << 2;
    float4 f = *(const float4*)(a.feat + (size_t)i * FEAT + j4);
    ushort4 o;
    o.x = f2bf(f.x); o.y = f2bf(f.y); o.z = f2bf(f.z); o.w = f2bf(f.w);
    *(ushort4*)(a.ajoin + (size_t)i * 640 + j4) = o;
    return;
  }
  int rel = bx - 16384;
  if (rel < 320) {           // join_w straight convert (640*512 = 81920 float4)
    int idx = rel * 256 + t;
    float4 f = *(const float4*)(a.join_w + (size_t)idx * 4);
    ushort4 o;
    o.x = f2bf(f.x); o.y = f2bf(f.y); o.z = f2bf(f.z); o.w = f2bf(f.w);
    *(ushort4*)(a.wjbf + (size_t)idx * 4) = o;
    return;
  }
  rel -= 320;
  if (rel < a.start[12]) {   // 32x32 transpose tiles
    int si = 0;
    while (rel >= a.start[si + 1]) ++si;
    WSeg sg = a.s[si];
    int tile = rel - a.start[si];
    int tkx = sg.K >> 5;
    int tn = tile / tkx;
    int tk = tile - tn * tkx;
    int k0 = tk * 32, n0 = tn * 32;
    __shared__ float tb[32][33];
    int tx = t & 31, ty = t >> 5;
#pragma unroll
    for (int j = 0; j < 4; ++j)
      tb[ty + j * 8][tx] = sg.src[(size_t)(k0 + ty + j * 8) * sg.N + n0 + tx];
    __syncthreads();
#pragma unroll
    for (int j = 0; j < 4; ++j)
      sg.dst[(size_t)(n0 + ty + j * 8) * sg.ldd + k0 + tx] = f2bf(tb[tx][ty + j * 8]);
    return;
  }
  rel -= a.start[12];
  // count blocks: per-wave ballot histogram
  int i = rel * 256 + t;
  int c = a.cmd[i];
  int wid = i >> 6;
  int lane = t & 63;
#pragma unroll
  for (int cv = 0; cv < NCMD; ++cv) {
    unsigned long long m = __ballot(c == cv);
    if (lane == 0) a.wavecnt[cv * 512 + wid] = __popcll(m);
  }
}

// --------- fused measured-speed module: speed -> v, into ajoin[:,512:640] -----
__launch_bounds__(256)
__global__ void k_ms(const float* __restrict__ speed,
                     const float* __restrict__ w1, const float* __restrict__ b1,
                     const unsigned short* __restrict__ w2t, const float* __restrict__ b2,
                     const unsigned short* __restrict__ w3t, const float* __restrict__ b3,
                     unsigned short* __restrict__ ajoin) {
  __shared__ unsigned short hw[128][136];
  __shared__ unsigned short Bs[128 * 32];
  const int m0 = blockIdx.x * 128;
  const int t = threadIdx.x;
  const int w = t >> 6, lane = t & 63;
  const int wm = w & 1, wn = w >> 1;
  const int fr = lane & 15, fk = (lane >> 4) * 8;
  const int rquad = (lane >> 4) * 4, cidx = lane & 15;

  {
    int r = t >> 1, half = t & 1;
    float s = speed[m0 + r];
#pragma unroll
    for (int c0 = 0; c0 < 64; c0 += 4) {
      int c = half * 64 + c0;
      float4 wv = *(const float4*)(w1 + c);
      float4 bv = *(const float4*)(b1 + c);
      hw[r][c + 0] = f2bf(fmaxf(fmaf(s, wv.x, bv.x), 0.f));
      hw[r][c + 1] = f2bf(fmaxf(fmaf(s, wv.y, bv.y), 0.f));
      hw[r][c + 2] = f2bf(fmaxf(fmaf(s, wv.z, bv.z), 0.f));
      hw[r][c + 3] = f2bf(fmaxf(fmaf(s, wv.w, bv.w), 0.f));
    }
  }
  __syncthreads();

  for (int layer = 0; layer < 2; ++layer) {
    const unsigned short* Wt = layer ? w3t : w2t;
    const float* bb = layer ? b3 : b2;
    f32x4 acc[4][4];
#pragma unroll
    for (int i = 0; i < 4; ++i)
#pragma unroll
      for (int j = 0; j < 4; ++j)
#pragma unroll
        for (int r = 0; r < 4; ++r) acc[i][j][r] = 0.f;

    for (int k0 = 0; k0 < 128; k0 += 32) {
#pragma unroll
      for (int it = 0; it < 2; ++it) {
        int row = w * 32 + it * 16 + (lane >> 2);
        async16(Wt + (size_t)row * 128 + k0 + (lane & 3) * 8,
                Bs + (w * 32 + it * 16) * 32);
      }
      __syncthreads();
      bf16x8 af[4], bfv[4];
#pragma unroll
      for (int i = 0; i < 4; ++i)
        af[i] = *(const bf16x8*)(&hw[wm * 64 + i * 16 + fr][k0 + fk]);
#pragma unroll
      for (int j = 0; j < 4; ++j)
        bfv[j] = *(const bf16x8*)(Bs + (wn * 64 + j * 16 + fr) * 32 + fk);
#pragma unroll
      for (int i = 0; i < 4; ++i)
#pragma unroll
        for (int j = 0; j < 4; ++j)
          acc[i][j] = __builtin_amdgcn_mfma_f32_16x16x32_bf16(af[i], bfv[j], acc[i][j], 0, 0, 0);
      __syncthreads();
    }
#pragma unroll
    for (int j = 0; j < 4; ++j) {
      int col = wn * 64 + j * 16 + cidx;
      float bv = bb[col];
#pragma unroll
      for (int i = 0; i < 4; ++i) {
        int row = wm * 64 + i * 16 + rquad;
#pragma unroll
        for (int r = 0; r < 4; ++r) {
          float v = acc[i][j][r] + bv;
          if (layer == 0) v = fmaxf(v, 0.f);
          hw[row + r][col] = f2bf(v);
        }
      }
    }
    __syncthreads();
  }
  {
    int r = t >> 1, half = t & 1;
#pragma unroll
    for (int c8 = 0; c8 < 8; ++c8)
      *(bf16x8*)(ajoin + (size_t)(m0 + r) * 640 + 512 + half * 64 + c8 * 8) =
          *(const bf16x8*)(&hw[r][half * 64 + c8 * 8]);
  }
}

// ---------------- 128x128 bf16 MFMA GEMM, bounce epilogue (r7-proven) ---------
// 1-D grid: m_tile = gid&255, n_tile = gid>>8; z = expert. bias may be null.
__launch_bounds__(256)
__global__ void k_gemm(const unsigned short* __restrict__ A, int lda,
                       const int* __restrict__ perm,
                       const int* __restrict__ seg,
                       const unsigned short* __restrict__ Wt, int wstride,
                       const float* __restrict__ bias, int bstride,
                       unsigned short* __restrict__ C, int ldc,
                       int relu_flag, int M, int K) {
  __shared__ unsigned short As[128 * 32];
  __shared__ unsigned short Bs[128 * 32];
  __shared__ float fscr[32][132];

  const int gid = blockIdx.x;
  const int mt = gid & 255;
  const int nt = gid >> 8;
  const int e = blockIdx.z;
  int m_start = 0, m_cnt = M;
  if (seg) { m_start = seg[e]; m_cnt = seg[e + 1] - m_start; }
  const int m0 = mt * 128;
  if (m0 >= m_cnt) return;
  const int n0 = nt * 128;
  const unsigned short* W = Wt + (size_t)e * wstride;
  const float* bi = bias ? (bias + (size_t)e * bstride) : nullptr;

  const int t = threadIdx.x;
  const int w = t >> 6, lane = t & 63;
  const int wm = w & 1, wn = w >> 1;

  f32x4 acc[4][4];
#pragma unroll
  for (int i = 0; i < 4; ++i)
#pragma unroll
    for (int j = 0; j < 4; ++j)
#pragma unroll
      for (int r = 0; r < 4; ++r) acc[i][j][r] = 0.f;

  const int fr = lane & 15;
  const int fk = (lane >> 4) * 8;

  const unsigned short* agp[2]; const unsigned short* bgp[2];
  unsigned short* al[2]; unsigned short* bl[2];
#pragma unroll
  for (int it = 0; it < 2; ++it) {
    int row = w * 32 + it * 16 + (lane >> 2);
    int seg8 = (lane & 3) * 8;
    int rl = m0 + row;
    if (rl >= m_cnt) rl = m_cnt - 1;
    int grow = perm ? perm[m_start + rl] : (m_start + rl);
    agp[it] = A + (size_t)grow * lda + seg8;
    bgp[it] = W + (size_t)(n0 + row) * K + seg8;
    al[it] = As + (w * 32 + it * 16) * 32;
    bl[it] = Bs + (w * 32 + it * 16) * 32;
  }

  for (int k0 = 0; k0 < K; k0 += 32) {
#pragma unroll
    for (int it = 0; it < 2; ++it) {
      async16(agp[it] + k0, al[it]);
      async16(bgp[it] + k0, bl[it]);
    }
    __syncthreads();
    bf16x8 af[4], bfv[4];
#pragma unroll
    for (int i = 0; i < 4; ++i)
      af[i] = *(const bf16x8*)(As + (wm * 64 + i * 16 + fr) * 32 + fk);
#pragma unroll
    for (int j = 0; j < 4; ++j)
      bfv[j] = *(const bf16x8*)(Bs + (wn * 64 + j * 16 + fr) * 32 + fk);
#pragma unroll
    for (int i = 0; i < 4; ++i)
#pragma unroll
      for (int j = 0; j < 4; ++j)
        acc[i][j] = __builtin_amdgcn_mfma_f32_16x16x32_bf16(af[i], bfv[j], acc[i][j], 0, 0, 0);
    __syncthreads();
  }

  const int rquad = (lane >> 4) * 4;
  const int cidx = lane & 15;
  const bool rel = (relu_flag != 0);

  float bv[4];
#pragma unroll
  for (int j = 0; j < 4; ++j) bv[j] = bi ? bi[n0 + wn * 64 + j * 16 + cidx] : 0.f;

  // LDS-bounce epilogue: 4 chunks of 32 rows -> coalesced bf16 stores
#pragma unroll
  for (int c = 0; c < 4; ++c) {
    if (wm == (c >> 1)) {
#pragma unroll
      for (int j = 0; j < 4; ++j) {
#pragma unroll
        for (int ii = 0; ii < 2; ++ii) {
          int i = 2 * (c & 1) + ii;
          int lr = ii * 16 + rquad;
#pragma unroll
          for (int r = 0; r < 4; ++r) {
            float v = acc[i][j][r] + bv[j];
            if (rel) v = fmaxf(v, 0.f);
            fscr[lr + r][wn * 64 + j * 16 + cidx] = v;
          }
        }
      }
    }
    __syncthreads();
#pragma unroll
    for (int q = 0; q < 2; ++q) {
      int sg = t + 256 * q;
      int lr = sg >> 4, cs = (sg & 15) * 8;
      int grow = m0 + c * 32 + lr;
      if (grow < m_cnt) {
        union { bf16x8 v; unsigned short u[8]; } pk;
#pragma unroll
        for (int x = 0; x < 8; ++x) pk.u[x] = f2bf(fscr[lr][cs + x]);
        *(bf16x8*)(C + (size_t)(m_start + grow) * ldc + (n0 + cs)) = pk.v;
      }
    }
    __syncthreads();
  }
}

// ------- k_vgemm: 64xN256 GEMM + exact final dot, no C store ------------------
struct VArgs {
  const unsigned short* A_s; const unsigned short* A_c;
  const unsigned short* W_s; const unsigned short* W_c;
  const float* b_s; const float* b_c;
  const float* w3_s; const float* b3_s;
  const float* w3_c; const float* b3_c;
  const int* perm; const int* seg;
  float* out;
};
__launch_bounds__(256)
__global__ void k_vgemm(VArgs a) {
  __shared__ unsigned short As[64 * 32];
  __shared__ unsigned short Bs[256 * 32];
  const int z = blockIdx.z;
  const unsigned short* A; const unsigned short* W; const float* bi;
  int m_start, m_cnt;
  if (z == 4) { A = a.A_s; W = a.W_s; bi = a.b_s; m_start = 0; m_cnt = BB; }
  else {
    A = a.A_c; W = a.W_c + (size_t)z * 65536; bi = a.b_c + z * 256;
    m_start = a.seg[z]; m_cnt = a.seg[z + 1] - m_start;
  }
  const int m0 = blockIdx.x * 64;
  if (m0 >= m_cnt) return;
  const int t = threadIdx.x, w = t >> 6, lane = t & 63;
  const int fr = lane & 15, fk = (lane >> 4) * 8;

  f32x4 acc[16];
#pragma unroll
  for (int j = 0; j < 16; ++j)
#pragma unroll
    for (int r = 0; r < 4; ++r) acc[j][r] = 0.f;

  int arow = m0 + w * 16 + (lane >> 2);
  if (arow >= m_cnt) arow = m_cnt - 1;
  const unsigned short* ap = A + (size_t)(m_start + arow) * 256 + (lane & 3) * 8;
  unsigned short* al = As + (w * 16) * 32;
  const unsigned short* bp[4]; unsigned short* bl[4];
#pragma unroll
  for (int it = 0; it < 4; ++it) {
    int brow = w * 64 + it * 16 + (lane >> 2);
    bp[it] = W + (size_t)brow * 256 + (lane & 3) * 8;
    bl[it] = Bs + (w * 64 + it * 16) * 32;
  }

  for (int k0 = 0; k0 < 256; k0 += 32) {
    async16(ap + k0, al);
#pragma unroll
    for (int it = 0; it < 4; ++it) async16(bp[it] + k0, bl[it]);
    __syncthreads();
    bf16x8 af = *(const bf16x8*)(As + (w * 16 + fr) * 32 + fk);
#pragma unroll
    for (int j = 0; j < 16; ++j) {
      bf16x8 bfv = *(const bf16x8*)(Bs + (j * 16 + fr) * 32 + fk);
      acc[j] = __builtin_amdgcn_mfma_f32_16x16x32_bf16(af, bfv, acc[j], 0, 0, 0);
    }
    __syncthreads();
  }

  const int rquad = (lane >> 4) * 4;
  float bcol[16];
#pragma unroll
  for (int j = 0; j < 16; ++j) bcol[j] = bi[j * 16 + fr];

  if (z == 4) {
    float aw[16];
#pragma unroll
    for (int j = 0; j < 16; ++j) aw[j] = a.w3_s[j * 16 + fr];
#pragma unroll
    for (int r = 0; r < 4; ++r) {
      float s = 0.f;
#pragma unroll
      for (int j = 0; j < 16; ++j)
        s = fmaf(fmaxf(acc[j][r] + bcol[j], 0.f), aw[j], s);
      s += __shfl_xor(s, 1, 64);
      s += __shfl_xor(s, 2, 64);
      s += __shfl_xor(s, 4, 64);
      s += __shfl_xor(s, 8, 64);
      int row = m0 + w * 16 + rquad + r;
      if (fr == 0 && row < m_cnt) a.out[row] = s + a.b3_s[0];
    }
  } else {
    float aw0[16], aw1[16], aw2[16];
#pragma unroll
    for (int j = 0; j < 16; ++j) {
      const float* wp = a.w3_c + (size_t)z * 768 + (j * 16 + fr) * 3;
      aw0[j] = wp[0]; aw1[j] = wp[1]; aw2[j] = wp[2];
    }
#pragma unroll
    for (int r = 0; r < 4; ++r) {
      float s0 = 0.f, s1 = 0.f, s2 = 0.f;
#pragma unroll
      for (int j = 0; j < 16; ++j) {
        float v = fmaxf(acc[j][r] + bcol[j], 0.f);
        s0 = fmaf(v, aw0[j], s0);
        s1 = fmaf(v, aw1[j], s1);
        s2 = fmaf(v, aw2[j], s2);
      }
#pragma unroll
      for (int m = 1; m <= 8; m <<= 1) {
        s0 += __shfl_xor(s0, m, 64);
        s1 += __shfl_xor(s1, m, 64);
        s2 += __shfl_xor(s2, m, 64);
      }
      int row = m0 + w * 16 + rquad + r;
      if (fr == 0 && row < m_cnt) {
        int orig = a.perm[m_start + row];
        float a0 = s0 + a.b3_c[z * 3 + 0];
        float a1 = s1 + a.b3_c[z * 3 + 1];
        float a2 = s2 + a.b3_c[z * 3 + 2];
        a.out[BB + orig]     = 1.f / (1.f + __expf(-a0));   // throttle
        a.out[2 * BB + orig] = 1.f / (1.f + __expf(-a2));   // brake
        a.out[3 * BB + orig] = tanhf(a1);                   // steering
      }
    }
  }
}

// ---- place (self-scan) + 4 extra blocks computing fused ctrl1 bias b_f -------
__global__ void k_place(const int* __restrict__ cmd, const int* __restrict__ wavecnt,
                        int* __restrict__ perm, int* __restrict__ offs,
                        const float* __restrict__ join_b,
                        const float* __restrict__ ctrl_w1,
                        const float* __restrict__ ctrl_b1,
                        float* __restrict__ b_f) {
  int b = blockIdx.x, t = threadIdx.x;
  if (b >= 128) {            // b_f[e][n] = join_b . ctrl_w1[e][:,n] + ctrl_b1[e][n]
    int e = b - 128;
    float s = ctrl_b1[e * 256 + t];
    const float* w = ctrl_w1 + (size_t)e * 512 * 256 + t;
    for (int m = 0; m < 512; ++m) s = fmaf(join_b[m], w[(size_t)m * 256], s);
    b_f[e * 256 + t] = s;
    return;
  }
  __shared__ int pf[NCMD][4];
  __shared__ int tot[NCMD];
  int c = t >> 6, lane = t & 63;
  int v[8]; int s = 0;
#pragma unroll
  for (int q = 0; q < 8; ++q) { v[q] = wavecnt[c * 512 + lane * 8 + q]; s += v[q]; }
  int p = s;
#pragma unroll
  for (int m = 1; m < 64; m <<= 1) { int o = __shfl_up(p, m, 64); if (lane >= m) p += o; }
  int excl = p - s;
  if (lane == 63) tot[c] = p;
  if (lane == ((4 * b) >> 3)) {
    int base_off = (4 * b) & 7;
    int run = excl;
#pragma unroll
    for (int q = 0; q < 8; ++q) {
      if (q >= base_off && q < base_off + 4) pf[c][q - base_off] = run;
      run += v[q];
    }
  }
  __syncthreads();
  int soffs[NCMD + 1];
  soffs[0] = 0;
#pragma unroll
  for (int e = 0; e < NCMD; ++e) soffs[e + 1] = soffs[e] + tot[e];
  if (b == 0 && t == 0)
    for (int e = 0; e <= NCMD; ++e) offs[e] = soffs[e];
  int i = b * 256 + t;
  int mc = cmd[i];
  int lwid = t >> 6;
  int rank = 0, base = 0;
#pragma unroll
  for (int cv = 0; cv < NCMD; ++cv) {
    unsigned long long m = __ballot(mc == cv);
    if (mc == cv) {
      rank = __popcll(m & ((1ull << lane) - 1ull));
      base = soffs[cv] + pf[cv][lwid];
    }
  }
  perm[base + rank] = i;
}

static inline size_t align256(size_t x) { return (x + 255) & ~(size_t)255; }

extern "C" void kernel_launch(void* const* d_in, const int* in_sizes, int n_in,
                              void* d_out, int out_size, void* d_ws, size_t ws_size,
                              hipStream_t stream) {
  const float* feat   = (const float*)d_in[0];
  const float* speed  = (const float*)d_in[1];
  const int*   command= (const int*)d_in[2];
  const float* ms_w1  = (const float*)d_in[3];
  const float* ms_b1  = (const float*)d_in[4];
  const float* ms_w2  = (const float*)d_in[5];
  const float* ms_b2  = (const float*)d_in[6];
  const float* ms_w3  = (const float*)d_in[7];
  const float* ms_b3  = (const float*)d_in[8];
  const float* sp_w1  = (const float*)d_in[9];
  const float* sp_b1  = (const float*)d_in[10];
  const float* sp_w2  = (const float*)d_in[11];
  const float* sp_b2  = (const float*)d_in[12];
  const float* sp_w3  = (const float*)d_in[13];
  const float* sp_b3  = (const float*)d_in[14];
  const float* join_w = (const float*)d_in[15];
  const float* join_b = (const float*)d_in[16];
  const float* ctrl_w1= (const float*)d_in[17];
  const float* ctrl_b1= (const float*)d_in[18];
  const float* ctrl_w2= (const float*)d_in[19];
  const float* ctrl_b2= (const float*)d_in[20];
  const float* ctrl_w3= (const float*)d_in[21];
  const float* ctrl_b3= (const float*)d_in[22];
  float* out = (float*)d_out;

  char* ws = (char*)d_ws;
  size_t off = 0;
  auto alloc = [&](size_t bytes) -> char* { char* p = ws + off; off = align256(off + bytes); return p; };

  unsigned short* ajoin  = (unsigned short*)alloc((size_t)BB * 640 * 2);
  unsigned short* sph1   = (unsigned short*)alloc((size_t)BB * 256 * 2);
  unsigned short* ch1    = (unsigned short*)alloc((size_t)BB * 256 * 2);
  unsigned short* wtp    = (unsigned short*)alloc(1998848ull * 2);
  int* perm    = (int*)alloc((size_t)BB * 4);
  int* cnt     = (int*)alloc(64);        // offs[5] at cnt+4
  int* wavecnt = (int*)alloc(4 * 512 * 4);
  float* b_f   = (float*)alloc(4 * 256 * 4);

  unsigned short* sp_w1t = wtp;                 // [256][512]
  unsigned short* sp_w2t = wtp + 131072;        // [256][256]
  unsigned short* ms_w2t = wtp + 196608;        // [128][128]
  unsigned short* ms_w3t = wtp + 212992;        // [128][128]
  unsigned short* c_w1t  = wtp + 229376;        // [4][256][512]
  unsigned short* c_w2t  = wtp + 753664;        // [4][256][256]
  unsigned short* wjbf   = wtp + 1015808;       // [640][512] straight bf16
  unsigned short* wf_t   = wtp + 1343488;       // [4][256][640] fused W_f^T

  PrepArgs P;
  P.s[0] = { sp_w1, sp_w1t, 512, 256, 512 };
  P.s[1] = { sp_w2, sp_w2t, 256, 256, 256 };
  P.s[2] = { ms_w2, ms_w2t, 128, 128, 128 };
  P.s[3] = { ms_w3, ms_w3t, 128, 128, 128 };
  for (int e = 0; e < 4; ++e) P.s[4 + e] = { ctrl_w1 + (size_t)e * 512 * 256, c_w1t + (size_t)e * 131072, 512, 256, 512 };
  for (int e = 0; e < 4; ++e) P.s[8 + e] = { ctrl_w2 + (size_t)e * 256 * 256, c_w2t + (size_t)e * 65536, 256, 256, 256 };
  P.start[0] = 0;
  for (int i = 0; i < 12; ++i)
    P.start[i + 1] = P.start[i] + (P.s[i].K >> 5) * (P.s[i].N >> 5);
  P.join_w = join_w; P.wjbf = wjbf;
  P.feat = feat; P.ajoin = ajoin;
  P.cmd = command; P.wavecnt = wavecnt;
  int prep_blocks = 16384 + 320 + P.start[12] + 128;

  k_prep<<<prep_blocks, 256, 0, stream>>>(P);
  k_ms<<<256, 256, 0, stream>>>(speed, ms_w1, ms_b1, ms_w2t, ms_b2, ms_w3t, ms_b3, ajoin);
  k_place<<<132, 256, 0, stream>>>(command, wavecnt, perm, cnt + 4,
                                   join_b, ctrl_w1, ctrl_b1, b_f);

  // fuse: W_f^T[4][256][640] = c_w1t[4*256,512] @ wjbf[640,512]^T  (M=1024)
  k_gemm<<<5 * 256, 256, 0, stream>>>(c_w1t, 512, nullptr, nullptr,
      wjbf, 0, nullptr, 0, wf_t, 640, 0, 1024, 512);

  // sp1: sph1 = relu(feat_bf @ sp_w1 + b)   (A = ajoin cols 0..511, lda 640)
  k_gemm<<<2 * 256, 256, 0, stream>>>(ajoin, 640, nullptr, nullptr,
      sp_w1t, 0, sp_b1, 0, sph1, 256, 1, BB, 512);

  // ctrl1 fused: ch1 = relu(ajoin[perm] @ W_f[e] + b_f[e]), K=640
  k_gemm<<<dim3(2 * 256, 1, 4), 256, 0, stream>>>(ajoin, 640, perm, cnt + 4,
      wf_t, 256 * 640, b_f, 256, ch1, 256, 1, BB, 640);

  // sp2+v_p (z=4) and ctrl2+actions (z=0..3)
  VArgs V;
  V.A_s = sph1; V.A_c = ch1; V.W_s = sp_w2t; V.W_c = c_w2t;
  V.b_s = sp_b2; V.b_c = ctrl_b2;
  V.w3_s = sp_w3; V.b3_s = sp_b3; V.w3_c = ctrl_w3; V.b3_c = ctrl_b3;
  V.perm = perm; V.seg = cnt + 4; V.out = out;
  k_vgemm<<<dim3(512, 1, 5), 256, 0, stream>>>(V);
}

// Round 10
// 248.170 us; speedup vs baseline: 1.0788x; 1.0788x over previous
//
#include <hip/hip_runtime.h>
#include <hip/hip_bf16.h>
#include <stdint.h>
#include <math.h>

#define BB 32768
#define FEAT 512
#define SPD_H 128
#define CTRL_H 256
#define NCMD 4

typedef __attribute__((ext_vector_type(8))) short bf16x8;
typedef __attribute__((ext_vector_type(4))) float f32x4;

__device__ __forceinline__ unsigned short f2bf(float f) {
  union { float f; uint32_t u; } v; v.f = f;
  uint32_t u = v.u;
  return (unsigned short)((u + 0x7fffu + ((u >> 16) & 1u)) >> 16); // RNE
}

// async global->LDS, 16B per lane; LDS dest = wave-uniform base + lane*16
__device__ __forceinline__ void async16(const unsigned short* g, unsigned short* l) {
  __builtin_amdgcn_global_load_lds(
      (const __attribute__((address_space(1))) unsigned int*)g,
      (__attribute__((address_space(3))) unsigned int*)l, 16, 0, 0);
}

// ---------------- shared 128x128 bf16 MFMA GEMM tile (device fn) --------------
__device__ __forceinline__ void gemm128(
    const unsigned short* __restrict__ A, int lda,
    const int* __restrict__ perm, int m_start, int m_cnt,
    const unsigned short* __restrict__ W, const float* __restrict__ bi,
    unsigned short* __restrict__ C, int ldc, int relu, int K, int mt, int nt) {
  __shared__ unsigned short As[128 * 32];
  __shared__ unsigned short Bs[128 * 32];
  __shared__ float fscr[32][132];

  const int m0 = mt * 128;
  if (m0 >= m_cnt) return;
  const int n0 = nt * 128;
  const int t = threadIdx.x;
  const int w = t >> 6, lane = t & 63;
  const int wm = w & 1, wn = w >> 1;

  f32x4 acc[4][4];
#pragma unroll
  for (int i = 0; i < 4; ++i)
#pragma unroll
    for (int j = 0; j < 4; ++j)
#pragma unroll
      for (int r = 0; r < 4; ++r) acc[i][j][r] = 0.f;

  const int fr = lane & 15;
  const int fk = (lane >> 4) * 8;

  const unsigned short* agp[2]; const unsigned short* bgp[2];
  unsigned short* al[2]; unsigned short* bl[2];
#pragma unroll
  for (int it = 0; it < 2; ++it) {
    int row = w * 32 + it * 16 + (lane >> 2);
    int seg8 = (lane & 3) * 8;
    int rl = m0 + row;
    if (rl >= m_cnt) rl = m_cnt - 1;
    int grow = perm ? perm[m_start + rl] : (m_start + rl);
    agp[it] = A + (size_t)grow * lda + seg8;
    bgp[it] = W + (size_t)(n0 + row) * K + seg8;
    al[it] = As + (w * 32 + it * 16) * 32;
    bl[it] = Bs + (w * 32 + it * 16) * 32;
  }

  for (int k0 = 0; k0 < K; k0 += 32) {
#pragma unroll
    for (int it = 0; it < 2; ++it) {
      async16(agp[it] + k0, al[it]);
      async16(bgp[it] + k0, bl[it]);
    }
    __syncthreads();
    bf16x8 af[4], bfv[4];
#pragma unroll
    for (int i = 0; i < 4; ++i)
      af[i] = *(const bf16x8*)(As + (wm * 64 + i * 16 + fr) * 32 + fk);
#pragma unroll
    for (int j = 0; j < 4; ++j)
      bfv[j] = *(const bf16x8*)(Bs + (wn * 64 + j * 16 + fr) * 32 + fk);
#pragma unroll
    for (int i = 0; i < 4; ++i)
#pragma unroll
      for (int j = 0; j < 4; ++j)
        acc[i][j] = __builtin_amdgcn_mfma_f32_16x16x32_bf16(af[i], bfv[j], acc[i][j], 0, 0, 0);
    __syncthreads();
  }

  const int rquad = (lane >> 4) * 4;
  const int cidx = lane & 15;

  float bv[4];
#pragma unroll
  for (int j = 0; j < 4; ++j) bv[j] = bi ? bi[n0 + wn * 64 + j * 16 + cidx] : 0.f;

  // LDS-bounce epilogue: 4 chunks of 32 rows -> coalesced bf16 stores
#pragma unroll
  for (int c = 0; c < 4; ++c) {
    if (wm == (c >> 1)) {
#pragma unroll
      for (int j = 0; j < 4; ++j) {
#pragma unroll
        for (int ii = 0; ii < 2; ++ii) {
          int i = 2 * (c & 1) + ii;
          int lr = ii * 16 + rquad;
#pragma unroll
          for (int r = 0; r < 4; ++r) {
            float v = acc[i][j][r] + bv[j];
            if (relu) v = fmaxf(v, 0.f);
            fscr[lr + r][wn * 64 + j * 16 + cidx] = v;
          }
        }
      }
    }
    __syncthreads();
#pragma unroll
    for (int q = 0; q < 2; ++q) {
      int sg = t + 256 * q;
      int lr = sg >> 4, cs = (sg & 15) * 8;
      int grow = m0 + c * 32 + lr;
      if (grow < m_cnt) {
        union { bf16x8 v; unsigned short u[8]; } pk;
#pragma unroll
        for (int x = 0; x < 8; ++x) pk.u[x] = f2bf(fscr[lr][cs + x]);
        *(bf16x8*)(C + (size_t)(m_start + grow) * ldc + (n0 + cs)) = pk.v;
      }
    }
    __syncthreads();
  }
}

// ------ fused prep: feat convert + wjbf convert + transposes + count + b_f ----
struct WSeg { const float* src; unsigned short* dst; int K; int N; int ldd; };
struct PrepArgs {
  WSeg s[12];
  int start[13];
  const float* join_w; unsigned short* wjbf;   // straight f32->bf16, [640][512]
  const float* feat; unsigned short* ajoin;
  const int* cmd; int* wavecnt;
  const float* join_b; const float* ctrl_w1; const float* ctrl_b1; float* b_f;
};
__global__ void k_prep(PrepArgs a) {
  int bx = blockIdx.x, t = threadIdx.x;
  if (bx < 16384) {          // feat f32 -> bf16 into ajoin[:,0:512] (stride 640)
    int idx = bx * 256 + t;
    int i = idx >> 7;
    int j4 = (idx & 127) << 2;
    float4 f = *(const float4*)(a.feat + (size_t)i * FEAT + j4);
    ushort4 o;
    o.x = f2bf(f.x); o.y = f2bf(f.y); o.z = f2bf(f.z); o.w = f2bf(f.w);
    *(ushort4*)(a.ajoin + (size_t)i * 640 + j4) = o;
    return;
  }
  int rel = bx - 16384;
  if (rel < 320) {           // join_w straight convert (640*512/1024 float4/blk)
    int idx = rel * 256 + t;
    float4 f = *(const float4*)(a.join_w + (size_t)idx * 4);
    ushort4 o;
    o.x = f2bf(f.x); o.y = f2bf(f.y); o.z = f2bf(f.z); o.w = f2bf(f.w);
    *(ushort4*)(a.wjbf + (size_t)idx * 4) = o;
    return;
  }
  rel -= 320;
  if (rel < a.start[12]) {   // 32x32 transpose tiles
    int si = 0;
    while (rel >= a.start[si + 1]) ++si;
    WSeg sg = a.s[si];
    int tile = rel - a.start[si];
    int tkx = sg.K >> 5;
    int tn = tile / tkx;
    int tk = tile - tn * tkx;
    int k0 = tk * 32, n0 = tn * 32;
    __shared__ float tb[32][33];
    int tx = t & 31, ty = t >> 5;
#pragma unroll
    for (int j = 0; j < 4; ++j)
      tb[ty + j * 8][tx] = sg.src[(size_t)(k0 + ty + j * 8) * sg.N + n0 + tx];
    __syncthreads();
#pragma unroll
    for (int j = 0; j < 4; ++j)
      sg.dst[(size_t)(n0 + ty + j * 8) * sg.ldd + k0 + tx] = f2bf(tb[tx][ty + j * 8]);
    return;
  }
  rel -= a.start[12];
  if (rel < 128) {           // count blocks: per-wave ballot histogram
    int i = rel * 256 + t;
    int c = a.cmd[i];
    int wid = i >> 6;
    int lane = t & 63;
#pragma unroll
    for (int cv = 0; cv < NCMD; ++cv) {
      unsigned long long m = __ballot(c == cv);
      if (lane == 0) a.wavecnt[cv * 512 + wid] = __popcll(m);
    }
    return;
  }
  // b_f[e][n] = join_b . ctrl_w1[e][:,n] + ctrl_b1[e][n]   (4 blocks)
  int e = rel - 128;
  float s = a.ctrl_b1[e * 256 + t];
  const float* w = a.ctrl_w1 + (size_t)e * 512 * 256 + t;
  for (int m = 0; m < 512; ++m) s = fmaf(a.join_b[m], w[(size_t)m * 256], s);
  a.b_f[e * 256 + t] = s;
}

// --------- fused measured-speed module: speed -> v, into ajoin[:,512:640] -----
__launch_bounds__(256)
__global__ void k_ms(const float* __restrict__ speed,
                     const float* __restrict__ w1, const float* __restrict__ b1,
                     const unsigned short* __restrict__ w2t, const float* __restrict__ b2,
                     const unsigned short* __restrict__ w3t, const float* __restrict__ b3,
                     unsigned short* __restrict__ ajoin) {
  __shared__ unsigned short hw[128][136];
  __shared__ unsigned short Bs[128 * 32];
  const int m0 = blockIdx.x * 128;
  const int t = threadIdx.x;
  const int w = t >> 6, lane = t & 63;
  const int wm = w & 1, wn = w >> 1;
  const int fr = lane & 15, fk = (lane >> 4) * 8;
  const int rquad = (lane >> 4) * 4, cidx = lane & 15;

  {
    int r = t >> 1, half = t & 1;
    float s = speed[m0 + r];
#pragma unroll
    for (int c0 = 0; c0 < 64; c0 += 4) {
      int c = half * 64 + c0;
      float4 wv = *(const float4*)(w1 + c);
      float4 bv = *(const float4*)(b1 + c);
      hw[r][c + 0] = f2bf(fmaxf(fmaf(s, wv.x, bv.x), 0.f));
      hw[r][c + 1] = f2bf(fmaxf(fmaf(s, wv.y, bv.y), 0.f));
      hw[r][c + 2] = f2bf(fmaxf(fmaf(s, wv.z, bv.z), 0.f));
      hw[r][c + 3] = f2bf(fmaxf(fmaf(s, wv.w, bv.w), 0.f));
    }
  }
  __syncthreads();

  for (int layer = 0; layer < 2; ++layer) {
    const unsigned short* Wt = layer ? w3t : w2t;
    const float* bb = layer ? b3 : b2;
    f32x4 acc[4][4];
#pragma unroll
    for (int i = 0; i < 4; ++i)
#pragma unroll
      for (int j = 0; j < 4; ++j)
#pragma unroll
        for (int r = 0; r < 4; ++r) acc[i][j][r] = 0.f;

    for (int k0 = 0; k0 < 128; k0 += 32) {
#pragma unroll
      for (int it = 0; it < 2; ++it) {
        int row = w * 32 + it * 16 + (lane >> 2);
        async16(Wt + (size_t)row * 128 + k0 + (lane & 3) * 8,
                Bs + (w * 32 + it * 16) * 32);
      }
      __syncthreads();
      bf16x8 af[4], bfv[4];
#pragma unroll
      for (int i = 0; i < 4; ++i)
        af[i] = *(const bf16x8*)(&hw[wm * 64 + i * 16 + fr][k0 + fk]);
#pragma unroll
      for (int j = 0; j < 4; ++j)
        bfv[j] = *(const bf16x8*)(Bs + (wn * 64 + j * 16 + fr) * 32 + fk);
#pragma unroll
      for (int i = 0; i < 4; ++i)
#pragma unroll
        for (int j = 0; j < 4; ++j)
          acc[i][j] = __builtin_amdgcn_mfma_f32_16x16x32_bf16(af[i], bfv[j], acc[i][j], 0, 0, 0);
      __syncthreads();
    }
#pragma unroll
    for (int j = 0; j < 4; ++j) {
      int col = wn * 64 + j * 16 + cidx;
      float bv = bb[col];
#pragma unroll
      for (int i = 0; i < 4; ++i) {
        int row = wm * 64 + i * 16 + rquad;
#pragma unroll
        for (int r = 0; r < 4; ++r) {
          float v = acc[i][j][r] + bv;
          if (layer == 0) v = fmaxf(v, 0.f);
          hw[row + r][col] = f2bf(v);
        }
      }
    }
    __syncthreads();
  }
  {
    int r = t >> 1, half = t & 1;
#pragma unroll
    for (int c8 = 0; c8 < 8; ++c8)
      *(bf16x8*)(ajoin + (size_t)(m0 + r) * 640 + 512 + half * 64 + c8 * 8) =
          *(const bf16x8*)(&hw[r][half * 64 + c8 * 8]);
  }
}

// ------- k_mid: place (blocks 0..127) + W_f fuse GEMM (blocks 128..167) -------
struct MidArgs {
  const int* cmd; const int* wavecnt; int* perm; int* offs;
  const unsigned short* c_w1t; const unsigned short* wjbf; unsigned short* wf_t;
};
__launch_bounds__(256)
__global__ void k_mid(MidArgs a) {
  int b = blockIdx.x, t = threadIdx.x;
  if (b >= 128) {
    int idx = b - 128;                 // 0..39
    int mt = idx & 7, nt = idx >> 3;   // M=1024 -> 8 mtiles, N=640 -> 5 ntiles
    gemm128(a.c_w1t, 512, nullptr, 0, 1024, a.wjbf, nullptr, a.wf_t, 640, 0, 512, mt, nt);
    return;
  }
  __shared__ int pf[NCMD][4];
  __shared__ int tot[NCMD];
  int c = t >> 6, lane = t & 63;
  int v[8]; int s = 0;
#pragma unroll
  for (int q = 0; q < 8; ++q) { v[q] = a.wavecnt[c * 512 + lane * 8 + q]; s += v[q]; }
  int p = s;
#pragma unroll
  for (int m = 1; m < 64; m <<= 1) { int o = __shfl_up(p, m, 64); if (lane >= m) p += o; }
  int excl = p - s;
  if (lane == 63) tot[c] = p;
  if (lane == ((4 * b) >> 3)) {
    int base_off = (4 * b) & 7;
    int run = excl;
#pragma unroll
    for (int q = 0; q < 8; ++q) {
      if (q >= base_off && q < base_off + 4) pf[c][q - base_off] = run;
      run += v[q];
    }
  }
  __syncthreads();
  int soffs[NCMD + 1];
  soffs[0] = 0;
#pragma unroll
  for (int e = 0; e < NCMD; ++e) soffs[e + 1] = soffs[e] + tot[e];
  if (b == 0 && t == 0)
    for (int e = 0; e <= NCMD; ++e) a.offs[e] = soffs[e];
  int i = b * 256 + t;
  int mc = a.cmd[i];
  int lwid = t >> 6;
  int rank = 0, base = 0;
#pragma unroll
  for (int cv = 0; cv < NCMD; ++cv) {
    unsigned long long m = __ballot(mc == cv);
    if (mc == cv) {
      rank = __popcll(m & ((1ull << lane) - 1ull));
      base = soffs[cv] + pf[cv][lwid];
    }
  }
  a.perm[base + rank] = i;
}

// ------- k_main: z=0..3 fused ctrl1 (K=640, gathered), z=4 sp1 (K=512) --------
struct MainArgs {
  const unsigned short* ajoin;
  const unsigned short* wf_t; const float* b_f;
  const unsigned short* sp_w1t; const float* sp_b1;
  unsigned short* ch1; unsigned short* sph1;
  const int* perm; const int* seg;
};
__launch_bounds__(256)
__global__ void k_main(MainArgs a) {
  const int z = blockIdx.z;
  const int gid = blockIdx.x;
  const int mt = gid & 255, nt = gid >> 8;
  if (z == 4) {
    gemm128(a.ajoin, 640, nullptr, 0, BB, a.sp_w1t, a.sp_b1, a.sph1, 256, 1, 512, mt, nt);
  } else {
    int ms = a.seg[z], mc = a.seg[z + 1] - ms;
    gemm128(a.ajoin, 640, a.perm, ms, mc, a.wf_t + (size_t)z * 256 * 640,
            a.b_f + z * 256, a.ch1, 256, 1, 640, mt, nt);
  }
}

// ------- k_vgemm: 64xN256 GEMM + exact final dot, no C store ------------------
struct VArgs {
  const unsigned short* A_s; const unsigned short* A_c;
  const unsigned short* W_s; const unsigned short* W_c;
  const float* b_s; const float* b_c;
  const float* w3_s; const float* b3_s;
  const float* w3_c; const float* b3_c;
  const int* perm; const int* seg;
  float* out;
};
__launch_bounds__(256)
__global__ void k_vgemm(VArgs a) {
  __shared__ unsigned short As[64 * 32];
  __shared__ unsigned short Bs[256 * 32];
  const int z = blockIdx.z;
  const unsigned short* A; const unsigned short* W; const float* bi;
  int m_start, m_cnt;
  if (z == 4) { A = a.A_s; W = a.W_s; bi = a.b_s; m_start = 0; m_cnt = BB; }
  else {
    A = a.A_c; W = a.W_c + (size_t)z * 65536; bi = a.b_c + z * 256;
    m_start = a.seg[z]; m_cnt = a.seg[z + 1] - m_start;
  }
  const int m0 = blockIdx.x * 64;
  if (m0 >= m_cnt) return;
  const int t = threadIdx.x, w = t >> 6, lane = t & 63;
  const int fr = lane & 15, fk = (lane >> 4) * 8;

  f32x4 acc[16];
#pragma unroll
  for (int j = 0; j < 16; ++j)
#pragma unroll
    for (int r = 0; r < 4; ++r) acc[j][r] = 0.f;

  int arow = m0 + w * 16 + (lane >> 2);
  if (arow >= m_cnt) arow = m_cnt - 1;
  const unsigned short* ap = A + (size_t)(m_start + arow) * 256 + (lane & 3) * 8;
  unsigned short* al = As + (w * 16) * 32;
  const unsigned short* bp[4]; unsigned short* bl[4];
#pragma unroll
  for (int it = 0; it < 4; ++it) {
    int brow = w * 64 + it * 16 + (lane >> 2);
    bp[it] = W + (size_t)brow * 256 + (lane & 3) * 8;
    bl[it] = Bs + (w * 64 + it * 16) * 32;
  }

  for (int k0 = 0; k0 < 256; k0 += 32) {
    async16(ap + k0, al);
#pragma unroll
    for (int it = 0; it < 4; ++it) async16(bp[it] + k0, bl[it]);
    __syncthreads();
    bf16x8 af = *(const bf16x8*)(As + (w * 16 + fr) * 32 + fk);
#pragma unroll
    for (int j = 0; j < 16; ++j) {
      bf16x8 bfv = *(const bf16x8*)(Bs + (j * 16 + fr) * 32 + fk);
      acc[j] = __builtin_amdgcn_mfma_f32_16x16x32_bf16(af, bfv, acc[j], 0, 0, 0);
    }
    __syncthreads();
  }

  const int rquad = (lane >> 4) * 4;
  float bcol[16];
#pragma unroll
  for (int j = 0; j < 16; ++j) bcol[j] = bi[j * 16 + fr];

  if (z == 4) {
    float aw[16];
#pragma unroll
    for (int j = 0; j < 16; ++j) aw[j] = a.w3_s[j * 16 + fr];
#pragma unroll
    for (int r = 0; r < 4; ++r) {
      float s = 0.f;
#pragma unroll
      for (int j = 0; j < 16; ++j)
        s = fmaf(fmaxf(acc[j][r] + bcol[j], 0.f), aw[j], s);
      s += __shfl_xor(s, 1, 64);
      s += __shfl_xor(s, 2, 64);
      s += __shfl_xor(s, 4, 64);
      s += __shfl_xor(s, 8, 64);
      int row = m0 + w * 16 + rquad + r;
      if (fr == 0 && row < m_cnt) a.out[row] = s + a.b3_s[0];
    }
  } else {
    float aw0[16], aw1[16], aw2[16];
#pragma unroll
    for (int j = 0; j < 16; ++j) {
      const float* wp = a.w3_c + (size_t)z * 768 + (j * 16 + fr) * 3;
      aw0[j] = wp[0]; aw1[j] = wp[1]; aw2[j] = wp[2];
    }
#pragma unroll
    for (int r = 0; r < 4; ++r) {
      float s0 = 0.f, s1 = 0.f, s2 = 0.f;
#pragma unroll
      for (int j = 0; j < 16; ++j) {
        float v = fmaxf(acc[j][r] + bcol[j], 0.f);
        s0 = fmaf(v, aw0[j], s0);
        s1 = fmaf(v, aw1[j], s1);
        s2 = fmaf(v, aw2[j], s2);
      }
#pragma unroll
      for (int m = 1; m <= 8; m <<= 1) {
        s0 += __shfl_xor(s0, m, 64);
        s1 += __shfl_xor(s1, m, 64);
        s2 += __shfl_xor(s2, m, 64);
      }
      int row = m0 + w * 16 + rquad + r;
      if (fr == 0 && row < m_cnt) {
        int orig = a.perm[m_start + row];
        float a0 = s0 + a.b3_c[z * 3 + 0];
        float a1 = s1 + a.b3_c[z * 3 + 1];
        float a2 = s2 + a.b3_c[z * 3 + 2];
        a.out[BB + orig]     = 1.f / (1.f + __expf(-a0));   // throttle
        a.out[2 * BB + orig] = 1.f / (1.f + __expf(-a2));   // brake
        a.out[3 * BB + orig] = tanhf(a1);                   // steering
      }
    }
  }
}

static inline size_t align256(size_t x) { return (x + 255) & ~(size_t)255; }

extern "C" void kernel_launch(void* const* d_in, const int* in_sizes, int n_in,
                              void* d_out, int out_size, void* d_ws, size_t ws_size,
                              hipStream_t stream) {
  const float* feat   = (const float*)d_in[0];
  const float* speed  = (const float*)d_in[1];
  const int*   command= (const int*)d_in[2];
  const float* ms_w1  = (const float*)d_in[3];
  const float* ms_b1  = (const float*)d_in[4];
  const float* ms_w2  = (const float*)d_in[5];
  const float* ms_b2  = (const float*)d_in[6];
  const float* ms_w3  = (const float*)d_in[7];
  const float* ms_b3  = (const float*)d_in[8];
  const float* sp_w1  = (const float*)d_in[9];
  const float* sp_b1  = (const float*)d_in[10];
  const float* sp_w2  = (const float*)d_in[11];
  const float* sp_b2  = (const float*)d_in[12];
  const float* sp_w3  = (const float*)d_in[13];
  const float* sp_b3  = (const float*)d_in[14];
  const float* join_w = (const float*)d_in[15];
  const float* join_b = (const float*)d_in[16];
  const float* ctrl_w1= (const float*)d_in[17];
  const float* ctrl_b1= (const float*)d_in[18];
  const float* ctrl_w2= (const float*)d_in[19];
  const float* ctrl_b2= (const float*)d_in[20];
  const float* ctrl_w3= (const float*)d_in[21];
  const float* ctrl_b3= (const float*)d_in[22];
  float* out = (float*)d_out;

  char* ws = (char*)d_ws;
  size_t off = 0;
  auto alloc = [&](size_t bytes) -> char* { char* p = ws + off; off = align256(off + bytes); return p; };

  unsigned short* ajoin  = (unsigned short*)alloc((size_t)BB * 640 * 2);
  unsigned short* sph1   = (unsigned short*)alloc((size_t)BB * 256 * 2);
  unsigned short* ch1    = (unsigned short*)alloc((size_t)BB * 256 * 2);
  unsigned short* wtp    = (unsigned short*)alloc(1998848ull * 2);
  int* perm    = (int*)alloc((size_t)BB * 4);
  int* cnt     = (int*)alloc(64);        // offs[5] at cnt+4
  int* wavecnt = (int*)alloc(4 * 512 * 4);
  float* b_f   = (float*)alloc(4 * 256 * 4);

  unsigned short* sp_w1t = wtp;                 // [256][512]
  unsigned short* sp_w2t = wtp + 131072;        // [256][256]
  unsigned short* ms_w2t = wtp + 196608;        // [128][128]
  unsigned short* ms_w3t = wtp + 212992;        // [128][128]
  unsigned short* c_w1t  = wtp + 229376;        // [4][256][512]
  unsigned short* c_w2t  = wtp + 753664;        // [4][256][256]
  unsigned short* wjbf   = wtp + 1015808;       // [640][512] straight bf16
  unsigned short* wf_t   = wtp + 1343488;       // [4][256][640] fused W_f^T

  PrepArgs P;
  P.s[0] = { sp_w1, sp_w1t, 512, 256, 512 };
  P.s[1] = { sp_w2, sp_w2t, 256, 256, 256 };
  P.s[2] = { ms_w2, ms_w2t, 128, 128, 128 };
  P.s[3] = { ms_w3, ms_w3t, 128, 128, 128 };
  for (int e = 0; e < 4; ++e) P.s[4 + e] = { ctrl_w1 + (size_t)e * 512 * 256, c_w1t + (size_t)e * 131072, 512, 256, 512 };
  for (int e = 0; e < 4; ++e) P.s[8 + e] = { ctrl_w2 + (size_t)e * 256 * 256, c_w2t + (size_t)e * 65536, 256, 256, 256 };
  P.start[0] = 0;
  for (int i = 0; i < 12; ++i)
    P.start[i + 1] = P.start[i] + (P.s[i].K >> 5) * (P.s[i].N >> 5);
  P.join_w = join_w; P.wjbf = wjbf;
  P.feat = feat; P.ajoin = ajoin;
  P.cmd = command; P.wavecnt = wavecnt;
  P.join_b = join_b; P.ctrl_w1 = ctrl_w1; P.ctrl_b1 = ctrl_b1; P.b_f = b_f;
  int prep_blocks = 16384 + 320 + P.start[12] + 128 + 4;

  k_prep<<<prep_blocks, 256, 0, stream>>>(P);
  k_ms<<<256, 256, 0, stream>>>(speed, ms_w1, ms_b1, ms_w2t, ms_b2, ms_w3t, ms_b3, ajoin);

  MidArgs Mi;
  Mi.cmd = command; Mi.wavecnt = wavecnt; Mi.perm = perm; Mi.offs = cnt + 4;
  Mi.c_w1t = c_w1t; Mi.wjbf = wjbf; Mi.wf_t = wf_t;
  k_mid<<<168, 256, 0, stream>>>(Mi);

  MainArgs Ma;
  Ma.ajoin = ajoin; Ma.wf_t = wf_t; Ma.b_f = b_f;
  Ma.sp_w1t = sp_w1t; Ma.sp_b1 = sp_b1;
  Ma.ch1 = ch1; Ma.sph1 = sph1;
  Ma.perm = perm; Ma.seg = cnt + 4;
  k_main<<<dim3(512, 1, 5), 256, 0, stream>>>(Ma);

  VArgs V;
  V.A_s = sph1; V.A_c = ch1; V.W_s = sp_w2t; V.W_c = c_w2t;
  V.b_s = sp_b2; V.b_c = ctrl_b2;
  V.w3_s = sp_w3; V.b3_s = sp_b3; V.w3_c = ctrl_w3; V.b3_c = ctrl_b3;
  V.perm = perm; V.seg = cnt + 4; V.out = out;
  k_vgemm<<<dim3(512, 1, 5), 256, 0, stream>>>(V);
}

// Round 12
// 237.613 us; speedup vs baseline: 1.1268x; 1.0444x over previous
//
#include <hip/hip_runtime.h>
#include <hip/hip_bf16.h>
#include <stdint.h>
#include <math.h>

#define BB 32768
#define FEAT 512
#define SPD_H 128
#define CTRL_H 256
#define NCMD 4

typedef __attribute__((ext_vector_type(8))) short bf16x8;
typedef __attribute__((ext_vector_type(4))) float f32x4;

__device__ __forceinline__ unsigned short f2bf(float f) {
  union { float f; uint32_t u; } v; v.f = f;
  uint32_t u = v.u;
  return (unsigned short)((u + 0x7fffu + ((u >> 16) & 1u)) >> 16); // RNE
}

// async global->LDS, 16B per lane; LDS dest = wave-uniform base + lane*16
__device__ __forceinline__ void async16(const unsigned short* g, unsigned short* l) {
  __builtin_amdgcn_global_load_lds(
      (const __attribute__((address_space(1))) unsigned int*)g,
      (__attribute__((address_space(3))) unsigned int*)l, 16, 0, 0);
}

// ---------------- shared 128x128 bf16 MFMA GEMM tile (device fn) --------------
// Uses 16 KB of DYNAMIC LDS: As|Bs during k-loop, bf16 bounce in epilogue.
__device__ __forceinline__ void gemm128(
    const unsigned short* __restrict__ A, int lda,
    const int* __restrict__ perm, int m_start, int m_cnt,
    const unsigned short* __restrict__ W, const float* __restrict__ bi,
    unsigned short* __restrict__ C, int ldc, int relu, int K, int mt, int nt) {
  extern __shared__ __align__(16) unsigned char dynsm[];
  unsigned short* As = (unsigned short*)dynsm;
  unsigned short* Bs = As + 128 * 32;

  const int m0 = mt * 128;
  if (m0 >= m_cnt) return;
  const int n0 = nt * 128;
  const int t = threadIdx.x;
  const int w = t >> 6, lane = t & 63;
  const int wm = w & 1, wn = w >> 1;

  f32x4 acc[4][4];
#pragma unroll
  for (int i = 0; i < 4; ++i)
#pragma unroll
    for (int j = 0; j < 4; ++j)
#pragma unroll
      for (int r = 0; r < 4; ++r) acc[i][j][r] = 0.f;

  const int fr = lane & 15;
  const int fk = (lane >> 4) * 8;

  const unsigned short* agp[2]; const unsigned short* bgp[2];
  unsigned short* al[2]; unsigned short* bl[2];
#pragma unroll
  for (int it = 0; it < 2; ++it) {
    int row = w * 32 + it * 16 + (lane >> 2);
    int seg8 = (lane & 3) * 8;
    int rl = m0 + row;
    if (rl >= m_cnt) rl = m_cnt - 1;
    int grow = perm ? perm[m_start + rl] : (m_start + rl);
    agp[it] = A + (size_t)grow * lda + seg8;
    bgp[it] = W + (size_t)(n0 + row) * K + seg8;
    al[it] = As + (w * 32 + it * 16) * 32;
    bl[it] = Bs + (w * 32 + it * 16) * 32;
  }

  for (int k0 = 0; k0 < K; k0 += 32) {
#pragma unroll
    for (int it = 0; it < 2; ++it) {
      async16(agp[it] + k0, al[it]);
      async16(bgp[it] + k0, bl[it]);
    }
    __syncthreads();
    bf16x8 af[4], bfv[4];
#pragma unroll
    for (int i = 0; i < 4; ++i)
      af[i] = *(const bf16x8*)(As + (wm * 64 + i * 16 + fr) * 32 + fk);
#pragma unroll
    for (int j = 0; j < 4; ++j)
      bfv[j] = *(const bf16x8*)(Bs + (wn * 64 + j * 16 + fr) * 32 + fk);
#pragma unroll
    for (int i = 0; i < 4; ++i)
#pragma unroll
      for (int j = 0; j < 4; ++j)
        acc[i][j] = __builtin_amdgcn_mfma_f32_16x16x32_bf16(af[i], bfv[j], acc[i][j], 0, 0, 0);
    __syncthreads();
  }

  const int rquad = (lane >> 4) * 4;
  const int cidx = lane & 15;

  float bv[4];
#pragma unroll
  for (int j = 0; j < 4; ++j) bv[j] = bi ? bi[n0 + wn * 64 + j * 16 + cidx] : 0.f;

  // bf16 LDS-bounce epilogue (reuses dynsm; As/Bs dead after k-loop barrier)
  unsigned short (*bscr)[136] = (unsigned short(*)[136])dynsm;
#pragma unroll
  for (int c = 0; c < 4; ++c) {
    if (wm == (c >> 1)) {
#pragma unroll
      for (int j = 0; j < 4; ++j) {
#pragma unroll
        for (int ii = 0; ii < 2; ++ii) {
          int i = 2 * (c & 1) + ii;
          int lr = ii * 16 + rquad;
#pragma unroll
          for (int r = 0; r < 4; ++r) {
            float v = acc[i][j][r] + bv[j];
            if (relu) v = fmaxf(v, 0.f);
            bscr[lr + r][wn * 64 + j * 16 + cidx] = f2bf(v);
          }
        }
      }
    }
    __syncthreads();
#pragma unroll
    for (int q = 0; q < 2; ++q) {
      int sg = t + 256 * q;
      int lr = sg >> 4, cs = (sg & 15) * 8;
      int grow = m0 + c * 32 + lr;
      if (grow < m_cnt)
        *(bf16x8*)(C + (size_t)(m_start + grow) * ldc + (n0 + cs)) =
            *(const bf16x8*)(&bscr[lr][cs]);
    }
    __syncthreads();
  }
}

// --- prep: feat convert + wjbf + transposes + count + b_f  (NO ms: see k_mid) -
struct WSeg { const float* src; unsigned short* dst; int K; int N; int ldd; };
struct PrepArgs {
  WSeg s[12];
  int start[13];
  const float* join_w; unsigned short* wjbf;
  const float* feat; unsigned short* ajoin;
  const int* cmd; int* wavecnt;
  const float* join_b; const float* ctrl_w1; const float* ctrl_b1; float* b_f;
};
__launch_bounds__(256)
__global__ void k_prep(PrepArgs a) {
  int bx = blockIdx.x, t = threadIdx.x;
  if (bx < 16384) {          // ---- feat f32 -> bf16 into ajoin[:,0:512]
    int idx = bx * 256 + t;
    int i = idx >> 7;
    int j4 = (idx & 127) << 2;
    float4 f = *(const float4*)(a.feat + (size_t)i * FEAT + j4);
    ushort4 o;
    o.x = f2bf(f.x); o.y = f2bf(f.y); o.z = f2bf(f.z); o.w = f2bf(f.w);
    *(ushort4*)(a.ajoin + (size_t)i * 640 + j4) = o;
    return;
  }
  int rel = bx - 16384;
  if (rel < 320) {           // ---- join_w straight convert
    int idx = rel * 256 + t;
    float4 f = *(const float4*)(a.join_w + (size_t)idx * 4);
    ushort4 o;
    o.x = f2bf(f.x); o.y = f2bf(f.y); o.z = f2bf(f.z); o.w = f2bf(f.w);
    *(ushort4*)(a.wjbf + (size_t)idx * 4) = o;
    return;
  }
  rel -= 320;
  if (rel < a.start[12]) {   // ---- 32x32 transpose tiles
    __shared__ float tb[32][33];
    int si = 0;
    while (rel >= a.start[si + 1]) ++si;
    WSeg sg = a.s[si];
    int tile = rel - a.start[si];
    int tkx = sg.K >> 5;
    int tn = tile / tkx;
    int tk = tile - tn * tkx;
    int k0 = tk * 32, n0 = tn * 32;
    int tx = t & 31, ty = t >> 5;
#pragma unroll
    for (int j = 0; j < 4; ++j)
      tb[ty + j * 8][tx] = sg.src[(size_t)(k0 + ty + j * 8) * sg.N + n0 + tx];
    __syncthreads();
#pragma unroll
    for (int j = 0; j < 4; ++j)
      sg.dst[(size_t)(n0 + ty + j * 8) * sg.ldd + k0 + tx] = f2bf(tb[tx][ty + j * 8]);
    return;
  }
  rel -= a.start[12];
  if (rel < 128) {           // ---- command count (ballot histogram)
    int i = rel * 256 + t;
    int c = a.cmd[i];
    int wid = i >> 6;
    int lane = t & 63;
#pragma unroll
    for (int cv = 0; cv < NCMD; ++cv) {
      unsigned long long m = __ballot(c == cv);
      if (lane == 0) a.wavecnt[cv * 512 + wid] = __popcll(m);
    }
    return;
  }
  // ---- b_f[e][n] = join_b . ctrl_w1[e][:,n] + ctrl_b1[e][n]
  int e = rel - 128;
  float s = a.ctrl_b1[e * 256 + t];
  const float* w = a.ctrl_w1 + (size_t)e * 512 * 256 + t;
  for (int m = 0; m < 512; ++m) s = fmaf(a.join_b[m], w[(size_t)m * 256], s);
  a.b_f[e * 256 + t] = s;
}

// -- k_mid: place (0..127) + W_f fuse GEMM (128..167) + ms module (168..423) ---
// ms is HERE (not k_prep) because it consumes ms_w2t/ms_w3t produced by k_prep:
// same-launch producer/consumer across blocks is a dispatch-order race (G16).
struct MidArgs {
  const int* cmd; const int* wavecnt; int* perm; int* offs;
  const unsigned short* c_w1t; const unsigned short* wjbf; unsigned short* wf_t;
  const float* speed;
  const float* ms_w1; const float* ms_b1;
  const unsigned short* ms_w2t; const float* ms_b2;
  const unsigned short* ms_w3t; const float* ms_b3;
  unsigned short* ajoin;
};
__launch_bounds__(256)
__global__ void k_mid(MidArgs a) {
  int b = blockIdx.x, t = threadIdx.x;
  if (b >= 168) {            // ---- measured-speed module (MFMA, LDS-resident)
    extern __shared__ __align__(16) unsigned char dynsm[];
    unsigned short (*hw)[136] = (unsigned short(*)[136])dynsm;
    unsigned short* BsM = (unsigned short*)(dynsm + 128 * 136 * 2);
    const int m0 = (b - 168) * 128;
    const int w = t >> 6, lane = t & 63;
    const int wm = w & 1, wn = w >> 1;
    const int fr = lane & 15, fk = (lane >> 4) * 8;
    const int rquad = (lane >> 4) * 4, cidx = lane & 15;
    {
      int r = t >> 1, half = t & 1;
      float s = a.speed[m0 + r];
#pragma unroll
      for (int c0 = 0; c0 < 64; c0 += 4) {
        int c = half * 64 + c0;
        float4 wv = *(const float4*)(a.ms_w1 + c);
        float4 bv = *(const float4*)(a.ms_b1 + c);
        hw[r][c + 0] = f2bf(fmaxf(fmaf(s, wv.x, bv.x), 0.f));
        hw[r][c + 1] = f2bf(fmaxf(fmaf(s, wv.y, bv.y), 0.f));
        hw[r][c + 2] = f2bf(fmaxf(fmaf(s, wv.z, bv.z), 0.f));
        hw[r][c + 3] = f2bf(fmaxf(fmaf(s, wv.w, bv.w), 0.f));
      }
    }
    __syncthreads();
    for (int layer = 0; layer < 2; ++layer) {
      const unsigned short* Wt = layer ? a.ms_w3t : a.ms_w2t;
      const float* bb = layer ? a.ms_b3 : a.ms_b2;
      f32x4 acc[4][4];
#pragma unroll
      for (int i = 0; i < 4; ++i)
#pragma unroll
        for (int j = 0; j < 4; ++j)
#pragma unroll
          for (int r = 0; r < 4; ++r) acc[i][j][r] = 0.f;
      for (int k0 = 0; k0 < 128; k0 += 32) {
#pragma unroll
        for (int it = 0; it < 2; ++it) {
          int row = w * 32 + it * 16 + (lane >> 2);
          async16(Wt + (size_t)row * 128 + k0 + (lane & 3) * 8,
                  BsM + (w * 32 + it * 16) * 32);
        }
        __syncthreads();
        bf16x8 af[4], bfv[4];
#pragma unroll
        for (int i = 0; i < 4; ++i)
          af[i] = *(const bf16x8*)(&hw[wm * 64 + i * 16 + fr][k0 + fk]);
#pragma unroll
        for (int j = 0; j < 4; ++j)
          bfv[j] = *(const bf16x8*)(BsM + (wn * 64 + j * 16 + fr) * 32 + fk);
#pragma unroll
        for (int i = 0; i < 4; ++i)
#pragma unroll
          for (int j = 0; j < 4; ++j)
            acc[i][j] = __builtin_amdgcn_mfma_f32_16x16x32_bf16(af[i], bfv[j], acc[i][j], 0, 0, 0);
        __syncthreads();
      }
#pragma unroll
      for (int j = 0; j < 4; ++j) {
        int col = wn * 64 + j * 16 + cidx;
        float bv = bb[col];
#pragma unroll
        for (int i = 0; i < 4; ++i) {
          int row = wm * 64 + i * 16 + rquad;
#pragma unroll
          for (int r = 0; r < 4; ++r) {
            float v = acc[i][j][r] + bv;
            if (layer == 0) v = fmaxf(v, 0.f);
            hw[row + r][col] = f2bf(v);
          }
        }
      }
      __syncthreads();
    }
    {
      int r = t >> 1, half = t & 1;
#pragma unroll
      for (int c8 = 0; c8 < 8; ++c8)
        *(bf16x8*)(a.ajoin + (size_t)(m0 + r) * 640 + 512 + half * 64 + c8 * 8) =
            *(const bf16x8*)(&hw[r][half * 64 + c8 * 8]);
    }
    return;
  }
  if (b >= 128) {            // ---- W_f fuse GEMM
    int idx = b - 128;                 // 0..39
    int mt = idx & 7, nt = idx >> 3;   // M=1024 -> 8 mtiles, N=640 -> 5 ntiles
    gemm128(a.c_w1t, 512, nullptr, 0, 1024, a.wjbf, nullptr, a.wf_t, 640, 0, 512, mt, nt);
    return;
  }
  // ---- place with per-block self-scan
  __shared__ int pf[NCMD][4];
  __shared__ int tot[NCMD];
  int c = t >> 6, lane = t & 63;
  int v[8]; int s = 0;
#pragma unroll
  for (int q = 0; q < 8; ++q) { v[q] = a.wavecnt[c * 512 + lane * 8 + q]; s += v[q]; }
  int p = s;
#pragma unroll
  for (int m = 1; m < 64; m <<= 1) { int o = __shfl_up(p, m, 64); if (lane >= m) p += o; }
  int excl = p - s;
  if (lane == 63) tot[c] = p;
  if (lane == ((4 * b) >> 3)) {
    int base_off = (4 * b) & 7;
    int run = excl;
#pragma unroll
    for (int q = 0; q < 8; ++q) {
      if (q >= base_off && q < base_off + 4) pf[c][q - base_off] = run;
      run += v[q];
    }
  }
  __syncthreads();
  int soffs[NCMD + 1];
  soffs[0] = 0;
#pragma unroll
  for (int e = 0; e < NCMD; ++e) soffs[e + 1] = soffs[e] + tot[e];
  if (b == 0 && t == 0)
    for (int e = 0; e <= NCMD; ++e) a.offs[e] = soffs[e];
  int i = b * 256 + t;
  int mc = a.cmd[i];
  int lwid = t >> 6;
  int rank = 0, base = 0;
#pragma unroll
  for (int cv = 0; cv < NCMD; ++cv) {
    unsigned long long m = __ballot(mc == cv);
    if (mc == cv) {
      rank = __popcll(m & ((1ull << lane) - 1ull));
      base = soffs[cv] + pf[cv][lwid];
    }
  }
  a.perm[base + rank] = i;
}

// ---- k_main: per expert z, gathered rows; nt<2: fused ctrl1; nt>=2: sp1 ------
// sp1 output sph1p is in PERMUTED row order (perm covers all B exactly once).
struct MainArgs {
  const unsigned short* ajoin;
  const unsigned short* wf_t; const float* b_f;
  const unsigned short* sp_w1t; const float* sp_b1;
  unsigned short* ch1; unsigned short* sph1p;
  const int* perm; const int* seg;
};
__launch_bounds__(256)
__global__ void k_main(MainArgs a) {
  const int e = blockIdx.z;
  const int gid = blockIdx.x;
  const int mt = gid & 255, nt = gid >> 8;
  int ms = a.seg[e], mc = a.seg[e + 1] - ms;
  if (nt < 2) {
    gemm128(a.ajoin, 640, a.perm, ms, mc, a.wf_t + (size_t)e * 256 * 640,
            a.b_f + e * 256, a.ch1, 256, 1, 640, mt, nt);
  } else {
    gemm128(a.ajoin, 640, a.perm, ms, mc, a.sp_w1t, a.sp_b1,
            a.sph1p, 256, 1, 512, mt, nt - 2);
  }
}

// ------- k_vgemm: 64xN256 GEMM + exact final dot, no C store ------------------
struct VArgs {
  const unsigned short* A_s; const unsigned short* A_c;
  const unsigned short* W_s; const unsigned short* W_c;
  const float* b_s; const float* b_c;
  const float* w3_s; const float* b3_s;
  const float* w3_c; const float* b3_c;
  const int* perm; const int* seg;
  float* out;
};
__launch_bounds__(256)
__global__ void k_vgemm(VArgs a) {
  __shared__ unsigned short As[64 * 32];
  __shared__ unsigned short Bs[256 * 32];
  const int z = blockIdx.z;
  const unsigned short* A; const unsigned short* W; const float* bi;
  int m_start, m_cnt;
  if (z == 4) { A = a.A_s; W = a.W_s; bi = a.b_s; m_start = 0; m_cnt = BB; }
  else {
    A = a.A_c; W = a.W_c + (size_t)z * 65536; bi = a.b_c + z * 256;
    m_start = a.seg[z]; m_cnt = a.seg[z + 1] - m_start;
  }
  const int m0 = blockIdx.x * 64;
  if (m0 >= m_cnt) return;
  const int t = threadIdx.x, w = t >> 6, lane = t & 63;
  const int fr = lane & 15, fk = (lane >> 4) * 8;

  f32x4 acc[16];
#pragma unroll
  for (int j = 0; j < 16; ++j)
#pragma unroll
    for (int r = 0; r < 4; ++r) acc[j][r] = 0.f;

  int arow = m0 + w * 16 + (lane >> 2);
  if (arow >= m_cnt) arow = m_cnt - 1;
  const unsigned short* ap = A + (size_t)(m_start + arow) * 256 + (lane & 3) * 8;
  unsigned short* al = As + (w * 16) * 32;
  const unsigned short* bp[4]; unsigned short* bl[4];
#pragma unroll
  for (int it = 0; it < 4; ++it) {
    int brow = w * 64 + it * 16 + (lane >> 2);
    bp[it] = W + (size_t)brow * 256 + (lane & 3) * 8;
    bl[it] = Bs + (w * 64 + it * 16) * 32;
  }

  for (int k0 = 0; k0 < 256; k0 += 32) {
    async16(ap + k0, al);
#pragma unroll
    for (int it = 0; it < 4; ++it) async16(bp[it] + k0, bl[it]);
    __syncthreads();
    bf16x8 af = *(const bf16x8*)(As + (w * 16 + fr) * 32 + fk);
#pragma unroll
    for (int j = 0; j < 16; ++j) {
      bf16x8 bfv = *(const bf16x8*)(Bs + (j * 16 + fr) * 32 + fk);
      acc[j] = __builtin_amdgcn_mfma_f32_16x16x32_bf16(af, bfv, acc[j], 0, 0, 0);
    }
    __syncthreads();
  }

  const int rquad = (lane >> 4) * 4;
  float bcol[16];
#pragma unroll
  for (int j = 0; j < 16; ++j) bcol[j] = bi[j * 16 + fr];

  if (z == 4) {
    float aw[16];
#pragma unroll
    for (int j = 0; j < 16; ++j) aw[j] = a.w3_s[j * 16 + fr];
#pragma unroll
    for (int r = 0; r < 4; ++r) {
      float s = 0.f;
#pragma unroll
      for (int j = 0; j < 16; ++j)
        s = fmaf(fmaxf(acc[j][r] + bcol[j], 0.f), aw[j], s);
      s += __shfl_xor(s, 1, 64);
      s += __shfl_xor(s, 2, 64);
      s += __shfl_xor(s, 4, 64);
      s += __shfl_xor(s, 8, 64);
      int row = m0 + w * 16 + rquad + r;
      if (fr == 0 && row < m_cnt)
        a.out[a.perm[row]] = s + a.b3_s[0];     // sph1p is permuted -> scatter
    }
  } else {
    float aw0[16], aw1[16], aw2[16];
#pragma unroll
    for (int j = 0; j < 16; ++j) {
      const float* wp = a.w3_c + (size_t)z * 768 + (j * 16 + fr) * 3;
      aw0[j] = wp[0]; aw1[j] = wp[1]; aw2[j] = wp[2];
    }
#pragma unroll
    for (int r = 0; r < 4; ++r) {
      float s0 = 0.f, s1 = 0.f, s2 = 0.f;
#pragma unroll
      for (int j = 0; j < 16; ++j) {
        float v = fmaxf(acc[j][r] + bcol[j], 0.f);
        s0 = fmaf(v, aw0[j], s0);
        s1 = fmaf(v, aw1[j], s1);
        s2 = fmaf(v, aw2[j], s2);
      }
#pragma unroll
      for (int m = 1; m <= 8; m <<= 1) {
        s0 += __shfl_xor(s0, m, 64);
        s1 += __shfl_xor(s1, m, 64);
        s2 += __shfl_xor(s2, m, 64);
      }
      int row = m0 + w * 16 + rquad + r;
      if (fr == 0 && row < m_cnt) {
        int orig = a.perm[m_start + row];
        float a0 = s0 + a.b3_c[z * 3 + 0];
        float a1 = s1 + a.b3_c[z * 3 + 1];
        float a2 = s2 + a.b3_c[z * 3 + 2];
        a.out[BB + orig]     = 1.f / (1.f + __expf(-a0));   // throttle
        a.out[2 * BB + orig] = 1.f / (1.f + __expf(-a2));   // brake
        a.out[3 * BB + orig] = tanhf(a1);                   // steering
      }
    }
  }
}

static inline size_t align256(size_t x) { return (x + 255) & ~(size_t)255; }

extern "C" void kernel_launch(void* const* d_in, const int* in_sizes, int n_in,
                              void* d_out, int out_size, void* d_ws, size_t ws_size,
                              hipStream_t stream) {
  const float* feat   = (const float*)d_in[0];
  const float* speed  = (const float*)d_in[1];
  const int*   command= (const int*)d_in[2];
  const float* ms_w1  = (const float*)d_in[3];
  const float* ms_b1  = (const float*)d_in[4];
  const float* ms_w2  = (const float*)d_in[5];
  const float* ms_b2  = (const float*)d_in[6];
  const float* ms_w3  = (const float*)d_in[7];
  const float* ms_b3  = (const float*)d_in[8];
  const float* sp_w1  = (const float*)d_in[9];
  const float* sp_b1  = (const float*)d_in[10];
  const float* sp_w2  = (const float*)d_in[11];
  const float* sp_b2  = (const float*)d_in[12];
  const float* sp_w3  = (const float*)d_in[13];
  const float* sp_b3  = (const float*)d_in[14];
  const float* join_w = (const float*)d_in[15];
  const float* join_b = (const float*)d_in[16];
  const float* ctrl_w1= (const float*)d_in[17];
  const float* ctrl_b1= (const float*)d_in[18];
  const float* ctrl_w2= (const float*)d_in[19];
  const float* ctrl_b2= (const float*)d_in[20];
  const float* ctrl_w3= (const float*)d_in[21];
  const float* ctrl_b3= (const float*)d_in[22];
  float* out = (float*)d_out;

  char* ws = (char*)d_ws;
  size_t off = 0;
  auto alloc = [&](size_t bytes) -> char* { char* p = ws + off; off = align256(off + bytes); return p; };

  unsigned short* ajoin  = (unsigned short*)alloc((size_t)BB * 640 * 2);
  unsigned short* sph1p  = (unsigned short*)alloc((size_t)BB * 256 * 2);
  unsigned short* ch1    = (unsigned short*)alloc((size_t)BB * 256 * 2);
  unsigned short* wtp    = (unsigned short*)alloc(1998848ull * 2);
  int* perm    = (int*)alloc((size_t)BB * 4);
  int* cnt     = (int*)alloc(64);        // offs[5] at cnt+4
  int* wavecnt = (int*)alloc(4 * 512 * 4);
  float* b_f   = (float*)alloc(4 * 256 * 4);

  unsigned short* sp_w1t = wtp;                 // [256][512]
  unsigned short* sp_w2t = wtp + 131072;        // [256][256]
  unsigned short* ms_w2t = wtp + 196608;        // [128][128]
  unsigned short* ms_w3t = wtp + 212992;        // [128][128]
  unsigned short* c_w1t  = wtp + 229376;        // [4][256][512]
  unsigned short* c_w2t  = wtp + 753664;        // [4][256][256]
  unsigned short* wjbf   = wtp + 1015808;       // [640][512] straight bf16
  unsigned short* wf_t   = wtp + 1343488;       // [4][256][640] fused W_f^T

  PrepArgs P;
  P.s[0] = { sp_w1, sp_w1t, 512, 256, 512 };
  P.s[1] = { sp_w2, sp_w2t, 256, 256, 256 };
  P.s[2] = { ms_w2, ms_w2t, 128, 128, 128 };
  P.s[3] = { ms_w3, ms_w3t, 128, 128, 128 };
  for (int e = 0; e < 4; ++e) P.s[4 + e] = { ctrl_w1 + (size_t)e * 512 * 256, c_w1t + (size_t)e * 131072, 512, 256, 512 };
  for (int e = 0; e < 4; ++e) P.s[8 + e] = { ctrl_w2 + (size_t)e * 256 * 256, c_w2t + (size_t)e * 65536, 256, 256, 256 };
  P.start[0] = 0;
  for (int i = 0; i < 12; ++i)
    P.start[i + 1] = P.start[i] + (P.s[i].K >> 5) * (P.s[i].N >> 5);
  P.join_w = join_w; P.wjbf = wjbf;
  P.feat = feat; P.ajoin = ajoin;
  P.cmd = command; P.wavecnt = wavecnt;
  P.join_b = join_b; P.ctrl_w1 = ctrl_w1; P.ctrl_b1 = ctrl_b1; P.b_f = b_f;
  int prep_blocks = 16384 + 320 + P.start[12] + 128 + 4;

  k_prep<<<prep_blocks, 256, 0, stream>>>(P);

  MidArgs Mi;
  Mi.cmd = command; Mi.wavecnt = wavecnt; Mi.perm = perm; Mi.offs = cnt + 4;
  Mi.c_w1t = c_w1t; Mi.wjbf = wjbf; Mi.wf_t = wf_t;
  Mi.speed = speed;
  Mi.ms_w1 = ms_w1; Mi.ms_b1 = ms_b1;
  Mi.ms_w2t = ms_w2t; Mi.ms_b2 = ms_b2;
  Mi.ms_w3t = ms_w3t; Mi.ms_b3 = ms_b3;
  Mi.ajoin = ajoin;
  k_mid<<<168 + 256, 256, 128 * 136 * 2 + 128 * 32 * 2, stream>>>(Mi);

  MainArgs Ma;
  Ma.ajoin = ajoin; Ma.wf_t = wf_t; Ma.b_f = b_f;
  Ma.sp_w1t = sp_w1t; Ma.sp_b1 = sp_b1;
  Ma.ch1 = ch1; Ma.sph1p = sph1p;
  Ma.perm = perm; Ma.seg = cnt + 4;
  k_main<<<dim3(1024, 1, 4), 256, 128 * 32 * 2 * 2, stream>>>(Ma);

  VArgs V;
  V.A_s = sph1p; V.A_c = ch1; V.W_s = sp_w2t; V.W_c = c_w2t;
  V.b_s = sp_b2; V.b_c = ctrl_b2;
  V.w3_s = sp_w3; V.b3_s = sp_b3; V.w3_c = ctrl_w3; V.b3_c = ctrl_b3;
  V.perm = perm; V.seg = cnt + 4; V.out = out;
  k_vgemm<<<dim3(512, 1, 5), 256, 0, stream>>>(V);
}